// Round 13
// baseline (688.016 us; speedup 1.0000x reference)
//
#include <hip/hip_runtime.h>
#include <math.h>

#define BB 64
#define CC 768
#define NN 1024
#define BS 192
#define EPS 1e-5f
#define LAM 0.01f

typedef float  f32x4  __attribute__((ext_vector_type(4)));
typedef short  bf16x8 __attribute__((ext_vector_type(8)));

__device__ inline unsigned f2bf(float x) {
    unsigned u = __float_as_uint(x);
    u += 0x7fff + ((u >> 16) & 1);   // RNE
    return u >> 16;
}
__device__ inline unsigned pack2(float r, float i) { return f2bf(r) | (f2bf(i) << 16); }
__device__ inline float bflo(unsigned v) { return __uint_as_float(v << 16); }
__device__ inline float bfhi(unsigned v) { return __uint_as_float(v & 0xffff0000u); }

// LDS bank swizzle on float2 index (FFT kernels): XOR bits 4-5 into bits 2-3.
// Bits 0-1 untouched -> swz(4t+j) == swz(4t)+j (4-consec groups stay contiguous).
__device__ inline int swz(int i) { return i ^ (((i >> 4) & 3) << 2); }

// Base-4 digit reversal of a 10-bit index (5 bit-pairs reversed).
__device__ inline int rev4(int p) {
    return ((p & 3) << 8) | ((p & 12) << 4) | (p & 48) | ((p >> 4) & 12) | ((p >> 8) & 3);
}
// Partner position holding frequency N-k for the position holding k.
__device__ inline int prt(int p) {
    return rev4((1024 - rev4(p)) & 1023);
}
__device__ inline float2 cmul(float2 z, float c, float s) {
    return make_float2(z.x * c - z.y * s, z.x * s + z.y * c);
}

// ---------------------------------------------------------------------------
// Kernel 1: LayerNorm statistics per (b, n). float4-vectorized along n.
// ---------------------------------------------------------------------------
__global__ __launch_bounds__(512) void ln_stats(const float* __restrict__ x,
                                                float* __restrict__ mu,
                                                float* __restrict__ rstd) {
    int tn = threadIdx.x & 63, tc = threadIdx.x >> 6;   // tc: 0..7
    int n = blockIdx.x * 256 + tn * 4, b = blockIdx.y;
    const float* xp = x + (size_t)b * CC * NN + n;
    f32x4 s = (f32x4)0.f, ss = (f32x4)0.f;
    #pragma unroll 4
    for (int c = tc; c < CC; c += 8) {
        f32x4 v = *(const f32x4*)(xp + (size_t)c * NN);
        s += v; ss += v * v;
    }
    __shared__ f32x4 sm[8][64], sq[8][64];
    sm[tc][tn] = s; sq[tc][tn] = ss;
    __syncthreads();
    if (tc == 0) {
        f32x4 S  = sm[0][tn], SS = sq[0][tn];
        #pragma unroll
        for (int i = 1; i < 8; i++) { S += sm[i][tn]; SS += sq[i][tn]; }
        f32x4 m = S * (1.f / 768.f);
        f32x4 r;
        #pragma unroll
        for (int i = 0; i < 4; i++) {
            float var = SS[i] * (1.f / 768.f) - m[i] * m[i];
            r[i] = rsqrtf(var + EPS);
        }
        *(f32x4*)(mu + (size_t)b * NN + n)   = m;
        *(f32x4*)(rstd + (size_t)b * NN + n) = r;
    }
}

// ---------------------------------------------------------------------------
// Kernel 2: LN-apply + q-DFT-first (real input) + 2 packed complex 1024-pt
// radix-4 DIF FFTs + conjugate-symmetry unpack + scale.
// Global I/O fully vectorized: thread t owns n = 4t..4t+3 at the boundary
// (f32x4 x/mu/rstd loads), q-DFT in registers, raw LDS write, then ALL 4
// stages (L=256,64,16,4) in LDS. Same math as R12, different schedule.
// ---------------------------------------------------------------------------
__global__ void fwd_fft(const float* __restrict__ x,
                        const float* __restrict__ mu_, const float* __restrict__ rs_,
                        const float* __restrict__ gamma, const float* __restrict__ beta,
                        unsigned* __restrict__ Xp) {
    __shared__ float2 bufs[2][1024];
    int d = blockIdx.x, b = blockIdx.y, tid = threadIdx.x;
    int n0 = 4 * tid;
    int i0 = swz(n0);

    // vectorized LN inputs
    f32x4 mu4 = *(const f32x4*)(mu_ + (size_t)b * NN + n0);
    f32x4 rs4 = *(const f32x4*)(rs_ + (size_t)b * NN + n0);
    f32x4 xq[4];
    #pragma unroll
    for (int q = 0; q < 4; q++) {
        int c = q * BS + d;
        float g = gamma[c], be = beta[c];
        f32x4 v = *(const f32x4*)(x + ((size_t)b * CC + c) * NN + n0);
        #pragma unroll
        for (int j = 0; j < 4; j++)
            v[j] = (v[j] - mu4[j]) * rs4[j] * g + be;
        xq[q] = v;
    }
    // q-DFT per n (real input): Za = U0 + i*U2, Zb = U1; raw-order LDS write
    #pragma unroll
    for (int j = 0; j < 4; j++) {
        float a = xq[0][j], b1v = xq[1][j], c2v = xq[2][j], d3v = xq[3][j];
        bufs[0][i0 + j] = make_float2(a + b1v + c2v + d3v, a - b1v + c2v - d3v);
        bufs[1][i0 + j] = make_float2(a - c2v, d3v - b1v);
    }
    __syncthreads();

    // radix-4 DIF stages, L = 256, 64, 16, 4, on 2 planes
    #pragma unroll
    for (int sL = 0; sL < 4; sL++) {
        const int L = 256 >> (2 * sL);
        int j = tid & (L - 1);
        int base = ((tid - j) << 2) + j;
        float s1, c1;
        __sincosf(-(float)M_PI * 0.5f * (float)j / (float)L, &s1, &c1);
        float c2 = c1 * c1 - s1 * s1, s2 = 2.f * c1 * s1;
        float c3 = c2 * c1 - s2 * s1, s3 = c2 * s1 + s2 * c1;
        #pragma unroll
        for (int pl = 0; pl < 2; pl++) {
            float2 a  = bufs[pl][swz(base)];
            float2 bb = bufs[pl][swz(base + L)];
            float2 cc = bufs[pl][swz(base + 2 * L)];
            float2 dd = bufs[pl][swz(base + 3 * L)];
            float t0r = a.x + cc.x, t0i = a.y + cc.y;
            float t1r = a.x - cc.x, t1i = a.y - cc.y;
            float t2r = bb.x + dd.x, t2i = bb.y + dd.y;
            float t3r = bb.x - dd.x, t3i = bb.y - dd.y;
            float X0r = t0r + t2r, X0i = t0i + t2i;
            float X2r = t0r - t2r, X2i = t0i - t2i;
            float X1r = t1r + t3i, X1i = t1i - t3r;
            float X3r = t1r - t3i, X3i = t1i + t3r;
            bufs[pl][swz(base)]         = make_float2(X0r, X0i);
            bufs[pl][swz(base + L)]     = make_float2(X1r * c1 - X1i * s1, X1r * s1 + X1i * c1);
            bufs[pl][swz(base + 2 * L)] = make_float2(X2r * c2 - X2i * s2, X2r * s2 + X2i * c2);
            bufs[pl][swz(base + 3 * L)] = make_float2(X3r * c3 - X3i * s3, X3r * s3 + X3i * c3);
        }
        __syncthreads();
    }

    // last stage (L=1, twiddle-free) in registers, then write back for gather
    float2 A[2][4];
    #pragma unroll
    for (int pl = 0; pl < 2; pl++) {
        const float4* p4 = (const float4*)&bufs[pl][i0];
        float4 v0 = p4[0], v1 = p4[1];
        float t0r = v0.x + v1.x, t0i = v0.y + v1.y;
        float t1r = v0.x - v1.x, t1i = v0.y - v1.y;
        float t2r = v0.z + v1.z, t2i = v0.w + v1.w;
        float t3r = v0.z - v1.z, t3i = v0.w - v1.w;
        A[pl][0] = make_float2(t0r + t2r, t0i + t2i);
        A[pl][1] = make_float2(t1r + t3i, t1i - t3r);   // t1 - i*t3
        A[pl][2] = make_float2(t0r - t2r, t0i - t2i);
        A[pl][3] = make_float2(t1r - t3i, t1i + t3r);   // t1 + i*t3
    }
    #pragma unroll
    for (int pl = 0; pl < 2; pl++)
        #pragma unroll
        for (int j = 0; j < 4; j++)
            bufs[pl][i0 + j] = A[pl][j];
    __syncthreads();

    // unpack via conjugate symmetry + scale + pack + uint4 stores
    const float sc  = 1.f / 64.f;    // planes 1,3 (direct)
    const float sc2 = 1.f / 128.f;   // planes 0,2 (un-halved symmetric sums)
    unsigned o0[4], o1[4], o2[4], o3[4];
    #pragma unroll
    for (int j = 0; j < 4; j++) {
        int p = n0 + j;
        int pq = prt(p);
        float2 zap = A[0][j], zbp = A[1][j];
        float2 zaq = bufs[0][swz(pq)];
        float2 zbq = bufs[1][swz(pq)];
        float p0r = zap.x + zaq.x, p0i = zap.y - zaq.y;
        float dr  = zap.x - zaq.x, di  = zap.y + zaq.y;
        o0[j] = pack2(p0r * sc2, p0i * sc2);
        o2[j] = pack2(di * sc2, -dr * sc2);
        o1[j] = pack2(zbp.x * sc, zbp.y * sc);      // X1 = Zb[k]
        o3[j] = pack2(zbq.x * sc, -zbq.y * sc);     // X3 = conj(Zb[N-k])
    }
    size_t qs = (size_t)BS * NN;
    size_t base = (((size_t)b * 4) * BS + d) * NN + n0;
    *(uint4*)(Xp + base)          = make_uint4(o0[0], o0[1], o0[2], o0[3]);
    *(uint4*)(Xp + base + qs)     = make_uint4(o1[0], o1[1], o1[2], o1[3]);
    *(uint4*)(Xp + base + 2 * qs) = make_uint4(o2[0], o2[1], o2[2], o2[3]);
    *(uint4*)(Xp + base + 3 * qs) = make_uint4(o3[0], o3[1], o3[2], o3[3]);
}

// ---------------------------------------------------------------------------
// Kernel 2b: one-time B prepack into flat [q][ch][j=384][dd=16] dwords.
// ---------------------------------------------------------------------------
__global__ void pack_b(const float* __restrict__ w, unsigned* __restrict__ Bp) {
    int ch = blockIdx.x, q = blockIdx.y;
    const float* wr = w + (size_t)q * BS * BS;
    const float* wi = w + (size_t)(4 + q) * BS * BS;
    size_t base = ((size_t)q * 12 + ch) * (384 * 16);
    for (int r = 0; r < 24; r++) {
        int idx = r * 256 + threadIdx.x;       // 0..6143
        int j = idx >> 4, dd = idx & 15;
        int h = j >> 1;
        int dg = ch * 16 + dd;
        float Wr = wr[(size_t)dg * BS + h];
        float Wi = wi[(size_t)dg * BS + h];
        Bp[base + idx] = (j & 1) ? pack2(Wi, Wr) : pack2(Wr, -Wi);
    }
}

// ---------------------------------------------------------------------------
// Kernel 3: FUSED complex MLP (R10 form — best measured). 512 threads =
// 8 j-waves; single 48 KB k-interleaved LDS panel shared for A then H.
// ---------------------------------------------------------------------------
__global__ __launch_bounds__(512) void fused_mlp(const unsigned* __restrict__ Ap,
                                                 const unsigned* __restrict__ Bp1,
                                                 const unsigned* __restrict__ Bp2,
                                                 const float* __restrict__ b1,
                                                 const float* __restrict__ b2,
                                                 unsigned* __restrict__ Yp) {
    __shared__ __align__(16) unsigned tl[12288];   // 48 KB shared panel

    const int mblk = blockIdx.x;   // 0..15 (64 m each)
    const int bq   = blockIdx.y;   // 0..255
    const int q    = bq & 3;
    const int tid  = threadIdx.x;
    const int wave = tid >> 6;     // 0..7: j-group, owns j = wave*48..+47
    const int lane = tid & 63;
    const int l15  = lane & 15;
    const int quad = lane >> 4;
    const int jw   = wave * 48;

    const size_t bstride = 384 * 16;   // dwords per (q,ch) slab
    const unsigned* b1_lane = Bp1 + (size_t)q * 12 * bstride + (jw + l15) * 16 + quad * 4;
    const unsigned* b2_lane = Bp2 + (size_t)q * 12 * bstride + (jw + l15) * 16 + quad * 4;

    // ---- stage A panel (192 rows x 64 cols) into k-interleaved LDS ----
    {
        const unsigned* abase = Ap + ((size_t)bq * BS) * NN + (size_t)mblk * 64;
        unsigned st[24];
        #pragma unroll
        for (int i = 0; i < 6; i++) {
            int r = (i * 8 + wave) * 4 + quad;
            const unsigned* gp = abase + (size_t)r * NN + l15;
            #pragma unroll
            for (int k = 0; k < 4; k++) st[i * 4 + k] = gp[16 * k];
        }
        #pragma unroll
        for (int i = 0; i < 6; i++) {
            int s = i * 8 + wave;
            unsigned* lp = &tl[s * 256 + quad];
            #pragma unroll
            for (int k = 0; k < 4; k++) lp[(l15 + 16 * k) * 4] = st[i * 4 + k];
        }
    }

    f32x4 acc[3][4];   // acc[tn][tm]
    #pragma unroll
    for (int i = 0; i < 3; i++)
        #pragma unroll
        for (int j = 0; j < 4; j++)
            acc[i][j] = (f32x4)0.f;

    __syncthreads();

    // ---- layer 1: 12 chunks; A-frags = 1 ds_read_b128 ----
    for (int ch = 0; ch < 12; ch++) {
        const unsigned* tp = &tl[(ch * 4 + quad) * 256];
        const unsigned* bp = b1_lane + ch * bstride;
        bf16x8 af[4], bfr[3];
        #pragma unroll
        for (int tm = 0; tm < 4; tm++)
            af[tm] = *(const bf16x8*)(tp + (tm * 16 + l15) * 4);
        #pragma unroll
        for (int tn = 0; tn < 3; tn++) {
            union { uint4 u4; bf16x8 v; } bu;
            bu.u4 = *(const uint4*)(bp + tn * 256);
            bfr[tn] = bu.v;
        }
        #pragma unroll
        for (int tn = 0; tn < 3; tn++)
            #pragma unroll
            for (int tm = 0; tm < 4; tm++)
                acc[tn][tm] = __builtin_amdgcn_mfma_f32_16x16x32_bf16(bfr[tn], af[tm], acc[tn][tm], 0, 0, 0);
    }

    __syncthreads();   // all waves done reading A before H overwrites

    // ---- epilogue 1: bias + ReLU -> bf16 pack -> H into same LDS ----
    #pragma unroll
    for (int tn = 0; tn < 3; tn++) {
        int hg = (jw >> 1) + tn * 8 + quad * 2;   // rows hg, hg+1
        float b0r = b1[q * BS + hg];
        float b0i = b1[768 + q * BS + hg];
        float b1r_ = b1[q * BS + hg + 1];
        float b1i_ = b1[768 + q * BS + hg + 1];
        #pragma unroll
        for (int tm = 0; tm < 4; tm++) {
            int c = tm * 16 + l15;
            f32x4 a = acc[tn][tm];
            float v0 = fmaxf(a[0] + b0r, 0.f);
            float v1 = fmaxf(a[1] + b0i, 0.f);
            float v2 = fmaxf(a[2] + b1r_, 0.f);
            float v3 = fmaxf(a[3] + b1i_, 0.f);
            unsigned* hp = &tl[(hg >> 2) * 256 + c * 4 + (hg & 3)];
            *(uint2*)hp = make_uint2(pack2(v0, v1), pack2(v2, v3));
            acc[tn][tm] = (f32x4)0.f;
        }
    }
    __syncthreads();

    // ---- layer 2: 12 chunks over H-LDS ----
    for (int ch = 0; ch < 12; ch++) {
        const unsigned* tp = &tl[(ch * 4 + quad) * 256];
        const unsigned* bp = b2_lane + ch * bstride;
        bf16x8 af[4], bfr[3];
        #pragma unroll
        for (int tm = 0; tm < 4; tm++)
            af[tm] = *(const bf16x8*)(tp + (tm * 16 + l15) * 4);
        #pragma unroll
        for (int tn = 0; tn < 3; tn++) {
            union { uint4 u4; bf16x8 v; } bu;
            bu.u4 = *(const uint4*)(bp + tn * 256);
            bfr[tn] = bu.v;
        }
        #pragma unroll
        for (int tn = 0; tn < 3; tn++)
            #pragma unroll
            for (int tm = 0; tm < 4; tm++)
                acc[tn][tm] = __builtin_amdgcn_mfma_f32_16x16x32_bf16(bfr[tn], af[tm], acc[tn][tm], 0, 0, 0);
    }

    // ---- epilogue 2: bias + softshrink -> Y plane stores ----
    #pragma unroll
    for (int tn = 0; tn < 3; tn++) {
        int hg = (jw >> 1) + tn * 8 + quad * 2;
        float b0r = b2[q * BS + hg];
        float b0i = b2[768 + q * BS + hg];
        float b1r_ = b2[q * BS + hg + 1];
        float b1i_ = b2[768 + q * BS + hg + 1];
        size_t row0 = ((size_t)bq * BS + hg) * NN + (size_t)mblk * 64;
        #pragma unroll
        for (int tm = 0; tm < 4; tm++) {
            int mcol = tm * 16 + l15;
            f32x4 a = acc[tn][tm];
            float v0 = a[0] + b0r, v1 = a[1] + b0i;
            float v2 = a[2] + b1r_, v3 = a[3] + b1i_;
            v0 = (v0 > LAM) ? (v0 - LAM) : ((v0 < -LAM) ? (v0 + LAM) : 0.f);
            v1 = (v1 > LAM) ? (v1 - LAM) : ((v1 < -LAM) ? (v1 + LAM) : 0.f);
            v2 = (v2 > LAM) ? (v2 - LAM) : ((v2 < -LAM) ? (v2 + LAM) : 0.f);
            v3 = (v3 > LAM) ? (v3 - LAM) : ((v3 < -LAM) ? (v3 + LAM) : 0.f);
            Yp[row0 + mcol]      = pack2(v0, v1);
            Yp[row0 + NN + mcol] = pack2(v2, v3);
        }
    }
}

// ---------------------------------------------------------------------------
// Kernel 4: inverse with Hermitian-part packing (2 inverse FFTs). All 4 DIT
// stages (L=4..256) in LDS; reconstruction + residual with f32x4 global I/O
// (thread t owns n = 4t..4t+3 at the boundary).
// ---------------------------------------------------------------------------
__global__ void inv_fft(const float* __restrict__ x,
                        const unsigned* __restrict__ Yp,
                        float* __restrict__ out) {
    __shared__ float2 bufs[4][1024];
    int d = blockIdx.x, b = blockIdx.y, tid = threadIdx.x;
    int n0 = 4 * tid;
    int i0 = swz(n0);

    // load all 4 planes at positions p = 4t..4t+3 (uint4)
    float2 S[4][4];
    size_t qs = (size_t)BS * NN;
    size_t rowb = (((size_t)b * 4) * BS + d) * NN + n0;
    #pragma unroll
    for (int u = 0; u < 4; u++) {
        uint4 v = *(const uint4*)(Yp + rowb + (size_t)u * qs);
        S[u][0] = make_float2(bflo(v.x), bfhi(v.x));
        S[u][1] = make_float2(bflo(v.y), bfhi(v.y));
        S[u][2] = make_float2(bflo(v.z), bfhi(v.z));
        S[u][3] = make_float2(bflo(v.w), bfhi(v.w));
    }
    #pragma unroll
    for (int u = 0; u < 4; u++)
        #pragma unroll
        for (int j = 0; j < 4; j++)
            bufs[u][i0 + j] = S[u][j];
    __syncthreads();

    // gather partners, build un-halved Hermitian parts
    float2 Wa[4], Wb[4];
    #pragma unroll
    for (int j = 0; j < 4; j++) {
        int p = n0 + j;
        int pq = prt(p);
        float2 s0q = bufs[0][swz(pq)];
        float2 s2q = bufs[2][swz(pq)];
        float2 s3q = bufs[3][swz(pq)];
        float h0r = S[0][j].x + s0q.x, h0i = S[0][j].y - s0q.y;
        float h2r = S[2][j].x + s2q.x, h2i = S[2][j].y - s2q.y;
        Wa[j] = make_float2(h0r - h2i, h0i + h2r);
        Wb[j] = make_float2(S[1][j].x + s3q.x, S[1][j].y - s3q.y);
    }
    __syncthreads();   // done reading S before overwriting planes 0,1

    // first DIT stage (twiddle-free, 4-consec) in registers -> LDS planes 0,1
    #pragma unroll
    for (int pl = 0; pl < 2; pl++) {
        float2 w0 = pl ? Wb[0] : Wa[0], w1 = pl ? Wb[1] : Wa[1];
        float2 w2 = pl ? Wb[2] : Wa[2], w3 = pl ? Wb[3] : Wa[3];
        float t0r = w0.x + w2.x, t0i = w0.y + w2.y;
        float t1r = w0.x - w2.x, t1i = w0.y - w2.y;
        float t2r = w1.x + w3.x, t2i = w1.y + w3.y;
        float t3r = w1.x - w3.x, t3i = w1.y - w3.y;
        bufs[pl][i0 + 0] = make_float2(t0r + t2r, t0i + t2i);
        bufs[pl][i0 + 1] = make_float2(t1r - t3i, t1i + t3r);  // t1 + i*t3
        bufs[pl][i0 + 2] = make_float2(t0r - t2r, t0i - t2i);
        bufs[pl][i0 + 3] = make_float2(t1r + t3i, t1i - t3r);  // t1 - i*t3
    }
    __syncthreads();

    // radix-4 DIT stages, L = 4, 16, 64, 256, on 2 planes (conjugate twiddles)
    #pragma unroll
    for (int sL = 0; sL < 4; sL++) {
        const int L = 4 << (2 * sL);
        int j = tid & (L - 1);
        int base = ((tid - j) << 2) + j;
        float s1, c1;
        __sincosf((float)M_PI * 0.5f * (float)j / (float)L, &s1, &c1);
        float c2 = c1 * c1 - s1 * s1, s2 = 2.f * c1 * s1;
        float c3 = c2 * c1 - s2 * s1, s3 = c2 * s1 + s2 * c1;
        #pragma unroll
        for (int pl = 0; pl < 2; pl++) {
            float2 y0 = bufs[pl][swz(base)];
            float2 y1 = bufs[pl][swz(base + L)];
            float2 y2 = bufs[pl][swz(base + 2 * L)];
            float2 y3 = bufs[pl][swz(base + 3 * L)];
            float A1r = y1.x * c1 - y1.y * s1, A1i = y1.x * s1 + y1.y * c1;
            float A2r = y2.x * c2 - y2.y * s2, A2i = y2.x * s2 + y2.y * c2;
            float A3r = y3.x * c3 - y3.y * s3, A3i = y3.x * s3 + y3.y * c3;
            float t0r = y0.x + A2r, t0i = y0.y + A2i;
            float t1r = y0.x - A2r, t1i = y0.y - A2i;
            float t2r = A1r + A3r, t2i = A1i + A3i;
            float t3r = A1r - A3r, t3i = A1i - A3i;
            bufs[pl][swz(base)]         = make_float2(t0r + t2r, t0i + t2i);
            bufs[pl][swz(base + L)]     = make_float2(t1r - t3i, t1i + t3r);
            bufs[pl][swz(base + 2 * L)] = make_float2(t0r - t2r, t0i - t2i);
            bufs[pl][swz(base + 3 * L)] = make_float2(t1r + t3i, t1i - t3r);
        }
        __syncthreads();
    }

    // reconstruction: thread t owns n = 4t..4t+3; f32x4 x-reads + out-stores
    float2 Va[4], Vb[4];
    {
        const float4* pa = (const float4*)&bufs[0][i0];
        const float4* pb = (const float4*)&bufs[1][i0];
        float4 a0 = pa[0], a1 = pa[1], b0 = pb[0], b1v = pb[1];
        Va[0] = make_float2(a0.x, a0.y); Va[1] = make_float2(a0.z, a0.w);
        Va[2] = make_float2(a1.x, a1.y); Va[3] = make_float2(a1.z, a1.w);
        Vb[0] = make_float2(b0.x, b0.y); Vb[1] = make_float2(b0.z, b0.w);
        Vb[2] = make_float2(b1v.x, b1v.y); Vb[3] = make_float2(b1v.z, b1v.w);
    }
    const float sc = 1.f / 128.f;   // (1/64 ortho) x (1/2 un-halved Hermitian)
    f32x4 y0v, y1v, y2v, y3v;
    #pragma unroll
    for (int j = 0; j < 4; j++) {
        float V0 = Va[j].x, V2 = Va[j].y;
        float R1 = Vb[j].x, I1 = Vb[j].y;
        y0v[j] = (V0 + V2 + 2.f * R1) * sc;
        y1v[j] = (V0 - V2 - 2.f * I1) * sc;
        y2v[j] = (V0 + V2 - 2.f * R1) * sc;
        y3v[j] = (V0 - V2 + 2.f * I1) * sc;
    }
    size_t row0 = (((size_t)b * 4 + 0) * BS + d) * NN + n0;
    size_t row1 = (((size_t)b * 4 + 1) * BS + d) * NN + n0;
    size_t row2 = (((size_t)b * 4 + 2) * BS + d) * NN + n0;
    size_t row3 = (((size_t)b * 4 + 3) * BS + d) * NN + n0;
    f32x4 x0 = *(const f32x4*)(x + row0);
    f32x4 x1 = *(const f32x4*)(x + row1);
    f32x4 x2 = *(const f32x4*)(x + row2);
    f32x4 x3 = *(const f32x4*)(x + row3);
    *(f32x4*)(out + row0) = y0v + x0;
    *(f32x4*)(out + row1) = y1v + x1;
    *(f32x4*)(out + row2) = y2v + x2;
    *(f32x4*)(out + row3) = y3v + x3;
}

// ---------------------------------------------------------------------------
extern "C" void kernel_launch(void* const* d_in, const int* in_sizes, int n_in,
                              void* d_out, int out_size, void* d_ws, size_t ws_size,
                              hipStream_t stream) {
    const float* x     = (const float*)d_in[0];
    const float* w1    = (const float*)d_in[1];
    const float* w2    = (const float*)d_in[2];
    const float* b1    = (const float*)d_in[3];
    const float* b2    = (const float*)d_in[4];
    const float* gamma = (const float*)d_in[5];
    const float* beta  = (const float*)d_in[6];

    unsigned* Xp = (unsigned*)d_ws;
    float* mu    = (float*)d_ws + (size_t)BB * CC * NN;
    float* rstd  = mu + (size_t)BB * NN;
    unsigned* Bp1 = (unsigned*)(rstd + (size_t)BB * NN);
    unsigned* Bp2 = Bp1 + (size_t)4 * 12 * 384 * 16;
    unsigned* Yp = Xp;   // layer-2 output overwrites X region (disjoint m-cols per block)

    pack_b<<<dim3(12, 4), 256, 0, stream>>>(w1, Bp1);
    pack_b<<<dim3(12, 4), 256, 0, stream>>>(w2, Bp2);
    ln_stats<<<dim3(NN / 256, BB), 512, 0, stream>>>(x, mu, rstd);
    fwd_fft<<<dim3(BS, BB), 256, 0, stream>>>(x, mu, rstd, gamma, beta, Xp);
    fused_mlp<<<dim3(16, 256), 512, 0, stream>>>(Xp, Bp1, Bp2, b1, b2, Yp);
    inv_fft<<<dim3(BS, BB), 256, 0, stream>>>(x, Yp, (float*)d_out);
}